// Round 1
// baseline (1095.460 us; speedup 1.0000x reference)
//
#include <hip/hip_runtime.h>

// LSTM decoder: B=2048, Z=64, A=8, H=512, T=64
// gates = x_proj + h @ W_hh^T ; bf16 MFMA 16x16x32, fp32 accumulate.

#define BATCH 2048
#define HID   512
#define TSTEP 64
#define NGATE 4

typedef __attribute__((ext_vector_type(8))) short bf16x8;   // 8 bf16 = 4 VGPR
typedef __attribute__((ext_vector_type(4))) float f32x4;

__device__ inline unsigned short f2bf(float f) {
  unsigned int u = __builtin_bit_cast(unsigned int, f);
  unsigned int r = (u + 0x7fffu + ((u >> 16) & 1u)) >> 16;
  return (unsigned short)r;
}
__device__ inline float sigm(float x) { return 1.0f / (1.0f + __expf(-x)); }
__device__ inline float tanh_f(float x) { return 1.0f - 2.0f / (__expf(2.0f * x) + 1.0f); }

// ---- W_hh (4H,512) f32 -> bf16, rearranged [nt 16][gate 4][r 32][k 512] ----
__global__ void k_warr(const float* __restrict__ whh, unsigned short* __restrict__ warr) {
  int g = blockIdx.x * 256 + threadIdx.x;          // 0 .. 2048*512-1
  int k = g & 511;
  int rl = g >> 9;                                  // (nt*4+gate)*32 + r
  int r = rl & 31, gt = (rl >> 5) & 3, nt = rl >> 7;
  int src_row = gt * HID + nt * 32 + r;
  warr[g] = f2bf(whh[(size_t)src_row * HID + k]);
}

// ---- x_proj[b][n] = b_ih[n]+b_hh[n] + sum_k z[b][k]*W_ih[n][8+k] ----
__global__ void k_xproj(const float* __restrict__ z, const float* __restrict__ wih,
                        const float* __restrict__ bih, const float* __restrict__ bhh,
                        float* __restrict__ xp) {
  __shared__ float zt[16][64];
  int n = blockIdx.x * 256 + threadIdx.x;           // 0..2047
  int b0 = blockIdx.y * 16;
  for (int i = threadIdx.x; i < 16 * 64; i += 256)
    zt[i >> 6][i & 63] = z[(size_t)(b0 + (i >> 6)) * 64 + (i & 63)];
  __syncthreads();
  float bias = bih[n] + bhh[n];
  float acc[16];
#pragma unroll
  for (int b = 0; b < 16; ++b) acc[b] = bias;
  const float* wr = wih + (size_t)n * 72 + 8;
  for (int k = 0; k < 64; ++k) {
    float w = wr[k];
#pragma unroll
    for (int b = 0; b < 16; ++b) acc[b] += zt[b][k] * w;
  }
#pragma unroll
  for (int b = 0; b < 16; ++b) xp[(size_t)(b0 + b) * 2048 + n] = acc[b];
}

// ---- out init (atomic fallback path only) ----
__global__ void k_initout(const float* __restrict__ bout, float* __restrict__ out) {
  int g = blockIdx.x * 256 + threadIdx.x;
  out[g] = bout[g & 7];
}

// ---- one LSTM step, fused cell + partial output projection ----
// grid (16 nt, 16 bt), 512 threads. WG tile: 128 batch x 32 hid x 4 gates.
template <int USE_ATOMIC>
__global__ __launch_bounds__(512) void k_step(
    const unsigned short* __restrict__ hprev, unsigned short* __restrict__ hcur,
    const float* __restrict__ xp, float* __restrict__ cst,
    const unsigned short* __restrict__ warr, const float* __restrict__ wout,
    float* __restrict__ proj_dst, int t) {
  const int nt = blockIdx.x, bt = blockIdx.y;
  const int tid = threadIdx.x;
  const int lane = tid & 63;
  const int wv = tid >> 6;        // 0..7
  const int mq = wv >> 1;         // 32-row group
  const int nh = wv & 1;          // 16-col half
  const int b0 = bt * 128;
  const int j0 = nt * 32;
  const int cl = lane & 15, q = lane >> 4;

  __shared__ unsigned short hA[128 * 72];  // 64 bf16 + 8 pad per row (144B stride)
  __shared__ unsigned short wB[128 * 72];
  __shared__ float hO[128][33];
  __shared__ float wo[8][33];

  if (tid < 256) { int a = tid >> 5, j = tid & 31; wo[a][j] = wout[(size_t)a * HID + j0 + j]; }

  // accumulator init = x_proj fragments (C/D layout: col=lane&15, row=(lane>>4)*4+reg)
  f32x4 acc[NGATE][2];
#pragma unroll
  for (int g4 = 0; g4 < NGATE; ++g4)
#pragma unroll
    for (int fm = 0; fm < 2; ++fm) {
      int brow = b0 + mq * 32 + fm * 16 + q * 4;
      const float* p = xp + (size_t)brow * 2048 + g4 * HID + j0 + nh * 16 + cl;
      f32x4 v; v[0] = p[0]; v[1] = p[2048]; v[2] = p[4096]; v[3] = p[6144];
      acc[g4][fm] = v;
    }

  if (t > 0) {
    const unsigned short* hsrc = hprev + (size_t)b0 * HID;
    const unsigned short* wsrc = warr + (size_t)nt * 128 * HID;
    const int sr = tid >> 3, sc = tid & 7;          // 2 rows each for h and W
    const size_t go1 = (size_t)sr * HID + sc * 8;
    const size_t go2 = (size_t)(sr + 64) * HID + sc * 8;
    const int lo1 = sr * 72 + sc * 8, lo2 = (sr + 64) * 72 + sc * 8;
    int4 ra = *(const int4*)(hsrc + go1);
    int4 rb = *(const int4*)(hsrc + go2);
    int4 rc = *(const int4*)(wsrc + go1);
    int4 rd = *(const int4*)(wsrc + go2);
    for (int kk = 0; kk < 8; ++kk) {                // BK=64, 8 iters over K=512
      __syncthreads();                              // prev-iter LDS reads done
      *(int4*)&hA[lo1] = ra; *(int4*)&hA[lo2] = rb;
      *(int4*)&wB[lo1] = rc; *(int4*)&wB[lo2] = rd;
      __syncthreads();
      if (kk < 7) {                                 // prefetch next chunk
        size_t kb = (size_t)(kk + 1) * 64;
        ra = *(const int4*)(hsrc + go1 + kb);
        rb = *(const int4*)(hsrc + go2 + kb);
        rc = *(const int4*)(wsrc + go1 + kb);
        rd = *(const int4*)(wsrc + go2 + kb);
      }
#pragma unroll
      for (int ks = 0; ks < 2; ++ks) {              // two K=32 sub-chunks
        bf16x8 af[2], bfr[NGATE];
#pragma unroll
        for (int fm = 0; fm < 2; ++fm)
          af[fm] = *(const bf16x8*)&hA[(mq * 32 + fm * 16 + cl) * 72 + ks * 32 + q * 8];
#pragma unroll
        for (int g4 = 0; g4 < NGATE; ++g4)
          bfr[g4] = *(const bf16x8*)&wB[(g4 * 32 + nh * 16 + cl) * 72 + ks * 32 + q * 8];
#pragma unroll
        for (int g4 = 0; g4 < NGATE; ++g4)
#pragma unroll
          for (int fm = 0; fm < 2; ++fm)
            acc[g4][fm] = __builtin_amdgcn_mfma_f32_16x16x32_bf16(af[fm], bfr[g4], acc[g4][fm], 0, 0, 0);
      }
    }
  }

  // ---- LSTM cell, fully in-register per lane ----
#pragma unroll
  for (int fm = 0; fm < 2; ++fm) {
    int brow = b0 + mq * 32 + fm * 16 + q * 4;
    int col = j0 + nh * 16 + cl;
#pragma unroll
    for (int r = 0; r < 4; ++r) {
      float iv = sigm(acc[0][fm][r]);
      float fv = sigm(acc[1][fm][r]);
      float gv = tanh_f(acc[2][fm][r]);
      float ov = sigm(acc[3][fm][r]);
      size_t cix = (size_t)(brow + r) * HID + col;
      float cp = (t > 0) ? cst[cix] : 0.0f;
      float cn = fv * cp + iv * gv;
      cst[cix] = cn;
      float hv = ov * tanh_f(cn);
      hcur[cix] = f2bf(hv);
      hO[mq * 32 + fm * 16 + q * 4 + r][nh * 16 + cl] = hv;
    }
  }
  __syncthreads();

  // ---- partial output projection: part[nt][b][t][a] = sum_j h[b][j0+j]*W_out[a][j0+j] ----
#pragma unroll
  for (int p = 0; p < 2; ++p) {
    int idx = tid * 2 + p;            // 0..1023 = 128 rows x 8 a
    int row = idx >> 3, a = idx & 7;
    float s = 0.0f;
#pragma unroll
    for (int j = 0; j < 32; ++j) s += hO[row][j] * wo[a][j];
    if (USE_ATOMIC) {
      atomicAdd(&proj_dst[((size_t)(b0 + row) * TSTEP + t) * 8 + a], s);
    } else {
      proj_dst[(((size_t)nt * BATCH + b0 + row) * TSTEP + t) * 8 + a] = s;
    }
  }
}

// ---- final reduce over nt partials + b_out ----
__global__ void k_final(const float* __restrict__ part, const float* __restrict__ bout,
                        float* __restrict__ out) {
  int g = blockIdx.x * 256 + threadIdx.x;     // out index = (b*64+t)*8+a
  float s = bout[g & 7];
#pragma unroll
  for (int n = 0; n < 16; ++n) s += part[(size_t)n * (BATCH * TSTEP * 8) + g];
  out[g] = s;
}

extern "C" void kernel_launch(void* const* d_in, const int* in_sizes, int n_in,
                              void* d_out, int out_size, void* d_ws, size_t ws_size,
                              hipStream_t stream) {
  const float* z    = (const float*)d_in[0];
  const float* wih  = (const float*)d_in[1];
  const float* whh  = (const float*)d_in[2];
  const float* bih  = (const float*)d_in[3];
  const float* bhh  = (const float*)d_in[4];
  const float* wout = (const float*)d_in[5];
  const float* bout = (const float*)d_in[6];
  float* out = (float*)d_out;

  char* ws = (char*)d_ws;
  float* xp            = (float*)(ws);                       // 16 MB
  float* cst           = (float*)(ws + (16u << 20));         // 4 MB
  unsigned short* h0   = (unsigned short*)(ws + (20u << 20));// 2 MB
  unsigned short* h1   = (unsigned short*)(ws + (22u << 20));// 2 MB
  unsigned short* warr = (unsigned short*)(ws + (24u << 20));// 2 MB
  float* part          = (float*)(ws + (26u << 20));         // 64 MB
  const size_t need_part = (26ull << 20) + 64ull * (1u << 20);
  const bool use_part = ws_size >= need_part;

  k_warr<<<dim3(4096), dim3(256), 0, stream>>>(whh, warr);
  k_xproj<<<dim3(8, 128), dim3(256), 0, stream>>>(z, wih, bih, bhh, xp);
  if (!use_part) k_initout<<<dim3(4096), dim3(256), 0, stream>>>(bout, out);

  for (int t = 0; t < TSTEP; ++t) {
    const unsigned short* hp = (t & 1) ? h0 : h1;
    unsigned short* hc = (t & 1) ? h1 : h0;
    if (use_part)
      k_step<0><<<dim3(16, 16), dim3(512), 0, stream>>>(hp, hc, xp, cst, warr, wout, part, t);
    else
      k_step<1><<<dim3(16, 16), dim3(512), 0, stream>>>(hp, hc, xp, cst, warr, wout, out, t);
  }
  if (use_part) k_final<<<dim3(4096), dim3(256), 0, stream>>>(part, bout, out);
}